// Round 7
// baseline (190.855 us; speedup 1.0000x reference)
//
#include <hip/hip_runtime.h>
#include <hip/hip_bf16.h>
#include <hip/hip_fp16.h>

#define B_  64
#define C_  32
#define N_  1152
#define DI_ 8
#define DC_ 16
#define NCH 3                // n's per staged chunk
#define NSLOT 128            // chunk-slots; slot handles chunks slot, +128, +256
#define STH 512              // 8 waves

static __device__ __forceinline__ unsigned pkh(float a, float b) {
    __half2 t = __float22half2_rn(make_float2(a, b));
    return *reinterpret_cast<unsigned*>(&t);
}
static __device__ __forceinline__ float2 uph(unsigned u) {
    __half2 h; *reinterpret_cast<unsigned*>(&h) = u;
    return __half22float2(h);
}

// ---------------- caps_hat: hat = W@x (fp32), store fp16, + s0 partials ----
// bq=4: wave covers 4 b's per LDS frag read -> LDS reads/CU 8640 -> 1728
// (R6 was LDS-pipe bound: 8640 x 12cyc = 43us of the 48us kernel).
// grid 256 = bg(2) x slot(128) = exactly 1 block/CU, balanced.
// 1 block/CU = 2 waves/EU -> launch_bounds(512,2) caps VGPR at 256: the
// ~120-reg live set (acc32+x32+w16+hq16+misc) fits with slack -> no spills.
__global__ __launch_bounds__(STH, 2) void caps_hat(
    const float* __restrict__ X, const float* __restrict__ W,
    uint4* __restrict__ hatg, float* __restrict__ p1)
{
    __shared__ float wlds[NCH * 64 * 64];    // 49,152 B : [nl][f=2c+h][phys quad q^(c&7)]
    __shared__ float xlds[NCH * 32 * 8];     //  3,072 B : [nl][b_local 32][8]

    const int bg   = blockIdx.x & 1;
    const int slot = blockIdx.x >> 1;
    const int tid  = threadIdx.x;
    const int w    = tid >> 6;
    const int lane = tid & 63;
    const int c    = lane & 31;
    const int h    = lane >> 5;
    const int bl0  = w * 4;                  // wave's 4 local b's
    const int le   = 2 * c + h;
    const int sw   = c & 7;

    float acc[4][8];
#pragma unroll
    for (int bq = 0; bq < 4; bq++)
#pragma unroll
        for (int r = 0; r < 8; r++) acc[bq][r] = 0.f;

    for (int cc = 0; cc < 3; cc++) {
        if (cc) __syncthreads();
        const int n0 = (slot + cc * NSLOT) * NCH;

        // stage W: 3072 float4 granules -> (nl, f=2c+h, quad q) at phys q^(wc&7)
        for (int G = tid; G < NCH * 1024; G += STH) {
            const int nl = G >> 10, f = (G >> 4) & 63, q = G & 15;
            const int wc = f >> 1, wh = f & 1;
            const float4 v = *(const float4*)(W + (size_t)(wc * N_ + n0 + nl) * 128 + wh * 64 + q * 4);
            *(float4*)(wlds + (nl * 64 + f) * 64 + (q ^ (wc & 7)) * 4) = v;
        }
        // stage X: 32 b x NCH n
        if (tid < NCH * 64) {
            const int nl = tid >> 6, bl = (tid >> 1) & 31, qx = tid & 1;
            const float4 v = *(const float4*)(X + (size_t)((bg * 32 + bl) * N_ + n0 + nl) * DI_ + qx * 4);
            *(float4*)(xlds + (nl * 32 + bl) * 8 + qx * 4) = v;
        }
        __syncthreads();

#pragma unroll
        for (int nl = 0; nl < NCH; nl++) {
            float4 xa[4], xb[4];
#pragma unroll
            for (int bq = 0; bq < 4; bq++) {
                const float* xp = xlds + (nl * 32 + bl0 + bq) * 8;   // wave-uniform broadcast
                xa[bq] = *(const float4*)xp;
                xb[bq] = *(const float4*)(xp + 4);
            }
            uint4 hq[4];
            const float* frag = wlds + (nl * 64 + le) * 64;
#pragma unroll
            for (int rp = 0; rp < 4; rp++) {             // r-pairs
                const int r0 = 2 * rp, r1 = r0 + 1;
                const int pa0 = ((2 * r0) ^ sw) * 4;     // swizzled quad offsets
                const int pb0 = pa0 ^ 4;
                const int pa1 = ((2 * r1) ^ sw) * 4;
                const int pb1 = pa1 ^ 4;
                const float4 wa0 = *(const float4*)(frag + pa0);
                const float4 wb0 = *(const float4*)(frag + pb0);
                const float4 wa1 = *(const float4*)(frag + pa1);
                const float4 wb1 = *(const float4*)(frag + pb1);
#pragma unroll
                for (int bq = 0; bq < 4; bq++) {
                    const float hv0 = wa0.x*xa[bq].x + wa0.y*xa[bq].y + wa0.z*xa[bq].z + wa0.w*xa[bq].w
                                    + wb0.x*xb[bq].x + wb0.y*xb[bq].y + wb0.z*xb[bq].z + wb0.w*xb[bq].w;
                    const float hv1 = wa1.x*xa[bq].x + wa1.y*xa[bq].y + wa1.z*xa[bq].z + wa1.w*xa[bq].w
                                    + wb1.x*xb[bq].x + wb1.y*xb[bq].y + wb1.z*xb[bq].z + wb1.w*xb[bq].w;
                    acc[bq][r0] += hv0;
                    acc[bq][r1] += hv1;
                    (&hq[bq].x)[rp] = pkh(hv0, hv1);
                }
            }
#pragma unroll
            for (int bq = 0; bq < 4; bq++) {
                const int b = bg * 32 + bl0 + bq;
                hatg[(size_t)(b * N_ + n0 + nl) * 64 + le] = hq[bq];
            }
        }
    }

    // slab = bg*NSLOT + slot : [32 b][512 e], e = le*8 + r; s0 scale 1/32 folded
    float* pout = p1 + (size_t)(bg * NSLOT + slot) * (32 * 512);
#pragma unroll
    for (int bq = 0; bq < 4; bq++) {
        float* pb = pout + (bl0 + bq) * 512 + le * 8;
        *(float4*)pb       = make_float4(acc[bq][0]*0.03125f, acc[bq][1]*0.03125f,
                                         acc[bq][2]*0.03125f, acc[bq][3]*0.03125f);
        *(float4*)(pb + 4) = make_float4(acc[bq][4]*0.03125f, acc[bq][5]*0.03125f,
                                         acc[bq][6]*0.03125f, acc[bq][7]*0.03125f);
    }
}

// ---------------- caps_route: one routing pass over materialized fp16 hat --
// block = (b, n-octant of 144). Wave owns 18 n's; in-block LDS reduction over
// the 8 waves -> one p2 slab per block (p2 shrinks 8.4 -> 1 MB vs R6).
__global__ __launch_bounds__(STH, 6) void caps_route(
    const uint4* __restrict__ hatg, const float* __restrict__ accb,
    float* __restrict__ p2)
{
    __shared__ float red[8 * 512];
    const int b    = blockIdx.x >> 3;
    const int oct  = blockIdx.x & 7;
    const int tid  = threadIdx.x;
    const int w    = tid >> 6;
    const int lane = tid & 63;
    const int c    = lane & 31;
    const int h    = lane >> 5;
    const int le   = 2 * c + h;

    const float* ap = accb + (size_t)b * 512 + le * 8;
    const float4 a0 = *(const float4*)ap;
    const float4 a1 = *(const float4*)(ap + 4);

    float acc[8] = {0.f,0.f,0.f,0.f,0.f,0.f,0.f,0.f};
    const uint4* hb = hatg + (size_t)(b * N_ + oct * 144) * 64 + le;

    for (int k = 0; k < 6; k++) {
        uint4 v[3];
#pragma unroll
        for (int u = 0; u < 3; u++)
            v[u] = hb[(size_t)(w + 8 * (3 * k + u)) * 64];
#pragma unroll
        for (int u = 0; u < 3; u++) {
            const float2 f0 = uph(v[u].x);
            const float2 f1 = uph(v[u].y);
            const float2 f2 = uph(v[u].z);
            const float2 f3 = uph(v[u].w);
            float lg = f0.x*a0.x + f0.y*a0.y + f1.x*a0.z + f1.y*a0.w
                     + f2.x*a1.x + f2.y*a1.y + f3.x*a1.z + f3.y*a1.w;
            lg += __shfl_xor(lg, 32, 64);        // combine i-halves (same c)
            const float e = __expf(lg);          // no max-subtract: |lg| small
            float s = e;
#pragma unroll
            for (int m = 16; m >= 1; m >>= 1) s += __shfl_xor(s, m, 64);
            const float sc = e * __builtin_amdgcn_rcpf(s);
            acc[0] += sc * f0.x; acc[1] += sc * f0.y;
            acc[2] += sc * f1.x; acc[3] += sc * f1.y;
            acc[4] += sc * f2.x; acc[5] += sc * f2.y;
            acc[6] += sc * f3.x; acc[7] += sc * f3.y;
        }
    }
    // block reduce over 8 waves
    *(float4*)(red + w * 512 + le * 8)     = make_float4(acc[0], acc[1], acc[2], acc[3]);
    *(float4*)(red + w * 512 + le * 8 + 4) = make_float4(acc[4], acc[5], acc[6], acc[7]);
    __syncthreads();
    float vs = 0.f;
#pragma unroll
    for (int s = 0; s < 8; s++) vs += red[s * 512 + tid];
    p2[(size_t)(b * 8 + oct) * 512 + tid] = vs;
}

// ---------------- caps_r1: reduce caps_hat's 128 slot-slabs (t=0) ----------
__global__ __launch_bounds__(256) void caps_r1(
    const float* __restrict__ p1, float* __restrict__ accb,
    float* __restrict__ out, int t)
{
    const int b   = blockIdx.x >> 2;
    const int q   = blockIdx.x & 3;
    const int tid = threadIdx.x;
    const int e   = q * 128 + (tid >> 1);
    const int p   = tid & 1;
    const int bg  = b >> 5, bl = b & 31;
    const float* base = p1 + (size_t)bg * NSLOT * 16384 + (size_t)bl * 512 + e;
    float v = 0.f;
#pragma unroll 8
    for (int ch = p; ch < NSLOT; ch += 2)
        v += base[(size_t)ch * 16384];
    v += __shfl_xor(v, 1, 64);
    float sq = v * v;
#pragma unroll
    for (int m = 2; m <= 16; m <<= 1) sq += __shfl_xor(sq, m, 64);
    const float scale = sq / (1.f + sq) * rsqrtf(sq + 1e-7f);
    const float ov = v * scale;
    if (p == 0) {
        const int oidx = b * 512 + e;
        if (t == 2) out[oidx] = ov;
        else        accb[oidx] = (t == 0) ? ov : (accb[oidx] + ov);
    }
}

// ---------------- caps_r2: reduce caps_route's 8 oct-slabs per b -----------
__global__ __launch_bounds__(512) void caps_r2(
    const float* __restrict__ p2, float* __restrict__ accb,
    float* __restrict__ out, int t)
{
    const int b = blockIdx.x;
    const int e = threadIdx.x;               // [c=e>>4][i=e&15]
    const float* base = p2 + (size_t)b * 4096 + e;
    float v = 0.f;
#pragma unroll
    for (int s = 0; s < 8; s++) v += base[s * 512];
    float sq = v * v;
#pragma unroll
    for (int m = 1; m <= 8; m <<= 1) sq += __shfl_xor(sq, m, 64);  // sum over i
    const float scale = sq / (1.f + sq) * rsqrtf(sq + 1e-7f);
    const float ov = v * scale;
    const int oidx = b * 512 + e;
    if (t == 2) out[oidx] = ov;
    else        accb[oidx] += ov;
}

// ---------------- fallback (R5 path, 16.9 MB ws) ---------------------------
__global__ __launch_bounds__(STH, 2) void caps_s_fb(
    const float* __restrict__ X, const float* __restrict__ W,
    const float* __restrict__ aout, float* __restrict__ partials, int t)
{
    __shared__ float wlds[NCH * 64 * 64];
    __shared__ float xlds[NCH * 16 * 8];
    const int bg = blockIdx.x & 3, slot = blockIdx.x >> 2;
    const int tid = threadIdx.x, w = tid >> 6, lane = tid & 63;
    const int c = lane & 31, h = lane >> 5, bl0 = w * 2, sw = c & 7;
    float areg[2][8] = {};
    if (t > 0) {
#pragma unroll
        for (int bq = 0; bq < 2; bq++) {
            const float* ap = aout + (size_t)(bg * 16 + bl0 + bq) * 512 + c * 16 + h * 8;
            const float4 a0 = *(const float4*)ap; const float4 a1 = *(const float4*)(ap + 4);
            areg[bq][0]=a0.x; areg[bq][1]=a0.y; areg[bq][2]=a0.z; areg[bq][3]=a0.w;
            areg[bq][4]=a1.x; areg[bq][5]=a1.y; areg[bq][6]=a1.z; areg[bq][7]=a1.w;
        }
    }
    float acc[2][8];
#pragma unroll
    for (int bq = 0; bq < 2; bq++)
#pragma unroll
        for (int r = 0; r < 8; r++) acc[bq][r] = 0.f;
    for (int cc = 0; cc < 3; cc++) {
        if (cc) __syncthreads();
        const int n0 = (slot + cc * NSLOT) * NCH;
        for (int G = tid; G < NCH * 1024; G += STH) {
            const int nl = G >> 10, f = (G >> 4) & 63, q = G & 15;
            const int wc = f >> 1, wh = f & 1;
            const float4 v = *(const float4*)(W + (size_t)(wc * N_ + n0 + nl) * 128 + wh * 64 + q * 4);
            *(float4*)(wlds + (nl * 64 + f) * 64 + (q ^ (wc & 7)) * 4) = v;
        }
        if (tid < NCH * 32) {
            const int nl = tid >> 5, bl = (tid >> 1) & 15, qx = tid & 1;
            const float4 v = *(const float4*)(X + (size_t)((bg * 16 + bl) * N_ + n0 + nl) * DI_ + qx * 4);
            *(float4*)(xlds + (nl * 16 + bl) * 8 + qx * 4) = v;
        }
        __syncthreads();
#pragma unroll
        for (int nl = 0; nl < NCH; nl++) {
            float4 xa[2], xb[2];
#pragma unroll
            for (int bq = 0; bq < 2; bq++) {
                const float* xp = xlds + (nl * 16 + bl0 + bq) * 8;
                xa[bq] = *(const float4*)xp; xb[bq] = *(const float4*)(xp + 4);
            }
            float hat[2][8];
            const float* frag = wlds + (nl * 64 + 2 * c + h) * 64;
#pragma unroll
            for (int r = 0; r < 8; r++) {
                const int pa = ((2 * r) ^ sw) * 4; const int pb = pa ^ 4;
                const float4 wa = *(const float4*)(frag + pa);
                const float4 wb = *(const float4*)(frag + pb);
#pragma unroll
                for (int bq = 0; bq < 2; bq++)
                    hat[bq][r] = wa.x*xa[bq].x + wa.y*xa[bq].y + wa.z*xa[bq].z + wa.w*xa[bq].w
                               + wb.x*xb[bq].x + wb.y*xb[bq].y + wb.z*xb[bq].z + wb.w*xb[bq].w;
            }
#pragma unroll
            for (int bq = 0; bq < 2; bq++) {
                float softc;
                if (t > 0) {
                    float lg = hat[bq][0]*areg[bq][0] + hat[bq][1]*areg[bq][1]
                             + hat[bq][2]*areg[bq][2] + hat[bq][3]*areg[bq][3]
                             + hat[bq][4]*areg[bq][4] + hat[bq][5]*areg[bq][5]
                             + hat[bq][6]*areg[bq][6] + hat[bq][7]*areg[bq][7];
                    lg += __shfl_xor(lg, 32, 64);
                    const float e = __expf(lg);
                    float s = e;
#pragma unroll
                    for (int m = 16; m >= 1; m >>= 1) s += __shfl_xor(s, m, 64);
                    softc = e / s;
                } else softc = 1.0f / 32.0f;
#pragma unroll
                for (int r = 0; r < 8; r++) acc[bq][r] += softc * hat[bq][r];
            }
        }
    }
    float* pout = partials + (size_t)(bg * NSLOT + slot) * (16 * 512);
#pragma unroll
    for (int bq = 0; bq < 2; bq++) {
        float* pb = pout + (bl0 + bq) * 512 + c * 16 + h * 8;
        *(float4*)pb       = make_float4(acc[bq][0], acc[bq][1], acc[bq][2], acc[bq][3]);
        *(float4*)(pb + 4) = make_float4(acc[bq][4], acc[bq][5], acc[bq][6], acc[bq][7]);
    }
}

__global__ __launch_bounds__(256) void caps_r1_fb(
    const float* __restrict__ partials, float* __restrict__ accb,
    float* __restrict__ out, int t)
{
    const int b   = blockIdx.x >> 2;
    const int q   = blockIdx.x & 3;
    const int tid = threadIdx.x;
    const int e   = q * 128 + (tid >> 1);
    const int p   = tid & 1;
    const int bg  = b >> 4, bl = b & 15;
    const float* base = partials + (size_t)bg * NSLOT * 8192 + (size_t)bl * 512 + e;
    float v = 0.f;
#pragma unroll 8
    for (int ch = p; ch < NSLOT; ch += 2)
        v += base[(size_t)ch * 8192];
    v += __shfl_xor(v, 1, 64);
    float sq = v * v;
#pragma unroll
    for (int m = 2; m <= 16; m <<= 1) sq += __shfl_xor(sq, m, 64);
    const float scale = sq / (1.f + sq) * rsqrtf(sq + 1e-7f);
    const float ov = v * scale;
    if (p == 0) {
        const int oidx = b * 512 + e;
        if (t == 2) out[oidx] = ov;
        else        accb[oidx] = (t == 0) ? ov : (accb[oidx] + ov);
    }
}

extern "C" void kernel_launch(void* const* d_in, const int* in_sizes, int n_in,
                              void* d_out, int out_size, void* d_ws, size_t ws_size,
                              hipStream_t stream) {
    const float* X = (const float*)d_in[0];   // [B,N,DI]
    const float* W = (const float*)d_in[1];   // [C,N,DC,DI]
    float* out = (float*)d_out;               // [B,C,DC]

    const size_t hat_b = (size_t)B_ * N_ * 512 * 2;      // 75,497,472 (fp16)
    const size_t p1_b  = (size_t)256 * 16384 * 4;        // 16,777,216
    const size_t p2_b  = (size_t)B_ * 8 * 512 * 4;       //  1,048,576
    const size_t acc_b = (size_t)B_ * 512 * 4;           //    131,072

    if (ws_size >= hat_b + p1_b + p2_b + acc_b) {
        char* ws = (char*)d_ws;
        uint4* hatg = (uint4*)ws;
        float* p1   = (float*)(ws + hat_b);
        float* p2   = (float*)(ws + hat_b + p1_b);
        float* accb = (float*)(ws + hat_b + p1_b + p2_b);
        caps_hat  <<<256, STH, 0, stream>>>(X, W, hatg, p1);
        caps_r1   <<<256, 256, 0, stream>>>(p1, accb, out, 0);
        caps_route<<<512, STH, 0, stream>>>(hatg, accb, p2);
        caps_r2   <<<64, 512, 0, stream>>>(p2, accb, out, 1);
        caps_route<<<512, STH, 0, stream>>>(hatg, accb, p2);
        caps_r2   <<<64, 512, 0, stream>>>(p2, accb, out, 2);
    } else {
        float* partials = (float*)d_ws;
        float* accb = partials + (size_t)512 * 8192;
        for (int t = 0; t < 3; t++) {
            caps_s_fb<<<512, STH, 0, stream>>>(X, W, accb, partials, t);
            caps_r1_fb<<<256, 256, 0, stream>>>(partials, accb, out, t);
        }
    }
}

// Round 8
// 130.047 us; speedup vs baseline: 1.4676x; 1.4676x over previous
//
#include <hip/hip_runtime.h>
#include <hip/hip_bf16.h>
#include <hip/hip_fp16.h>

#define B_  64
#define C_  32
#define N_  1152
#define DI_ 8
#define DC_ 16
#define NCH 3                // n's per staged chunk
#define NSLOT 128            // chunk-slots; slot handles chunks slot, +128, +256
#define STH 512              // 8 waves
#define NOCT 16              // route n-groups (72 n each): 1024 blocks = 4/CU

static __device__ __forceinline__ unsigned pkh(float a, float b) {
    __half2 t = __float22half2_rn(make_float2(a, b));
    return *reinterpret_cast<unsigned*>(&t);
}
static __device__ __forceinline__ float2 uph(unsigned u) {
    __half2 h; *reinterpret_cast<unsigned*>(&h) = u;
    return __half22float2(h);
}

// ---------------- caps_hat: hat = W@x (fp32), store fp16, + s0 partials ----
// bq=4: wave covers 4 b's per LDS frag read (R6 was LDS-pipe bound).
// grid 256 = bg(2) x slot(128) = 1 block/CU; (512,2) -> 256-VGPR cap, no spills.
__global__ __launch_bounds__(STH, 2) void caps_hat(
    const float* __restrict__ X, const float* __restrict__ W,
    uint4* __restrict__ hatg, float* __restrict__ p1)
{
    __shared__ float wlds[NCH * 64 * 64];    // [nl][f=2c+h][phys quad q^(c&7)]
    __shared__ float xlds[NCH * 32 * 8];     // [nl][b_local 32][8]

    const int bg   = blockIdx.x & 1;
    const int slot = blockIdx.x >> 1;
    const int tid  = threadIdx.x;
    const int w    = tid >> 6;
    const int lane = tid & 63;
    const int c    = lane & 31;
    const int h    = lane >> 5;
    const int bl0  = w * 4;
    const int le   = 2 * c + h;
    const int sw   = c & 7;

    float acc[4][8];
#pragma unroll
    for (int bq = 0; bq < 4; bq++)
#pragma unroll
        for (int r = 0; r < 8; r++) acc[bq][r] = 0.f;

    for (int cc = 0; cc < 3; cc++) {
        if (cc) __syncthreads();
        const int n0 = (slot + cc * NSLOT) * NCH;

        for (int G = tid; G < NCH * 1024; G += STH) {
            const int nl = G >> 10, f = (G >> 4) & 63, q = G & 15;
            const int wc = f >> 1, wh = f & 1;
            const float4 v = *(const float4*)(W + (size_t)(wc * N_ + n0 + nl) * 128 + wh * 64 + q * 4);
            *(float4*)(wlds + (nl * 64 + f) * 64 + (q ^ (wc & 7)) * 4) = v;
        }
        if (tid < NCH * 64) {
            const int nl = tid >> 6, bl = (tid >> 1) & 31, qx = tid & 1;
            const float4 v = *(const float4*)(X + (size_t)((bg * 32 + bl) * N_ + n0 + nl) * DI_ + qx * 4);
            *(float4*)(xlds + (nl * 32 + bl) * 8 + qx * 4) = v;
        }
        __syncthreads();

#pragma unroll
        for (int nl = 0; nl < NCH; nl++) {
            float4 xa[4], xb[4];
#pragma unroll
            for (int bq = 0; bq < 4; bq++) {
                const float* xp = xlds + (nl * 32 + bl0 + bq) * 8;
                xa[bq] = *(const float4*)xp;
                xb[bq] = *(const float4*)(xp + 4);
            }
            uint4 hq[4];
            const float* frag = wlds + (nl * 64 + le) * 64;
#pragma unroll
            for (int rp = 0; rp < 4; rp++) {
                const int r0 = 2 * rp, r1 = r0 + 1;
                const int pa0 = ((2 * r0) ^ sw) * 4;
                const int pb0 = pa0 ^ 4;
                const int pa1 = ((2 * r1) ^ sw) * 4;
                const int pb1 = pa1 ^ 4;
                const float4 wa0 = *(const float4*)(frag + pa0);
                const float4 wb0 = *(const float4*)(frag + pb0);
                const float4 wa1 = *(const float4*)(frag + pa1);
                const float4 wb1 = *(const float4*)(frag + pb1);
#pragma unroll
                for (int bq = 0; bq < 4; bq++) {
                    const float hv0 = wa0.x*xa[bq].x + wa0.y*xa[bq].y + wa0.z*xa[bq].z + wa0.w*xa[bq].w
                                    + wb0.x*xb[bq].x + wb0.y*xb[bq].y + wb0.z*xb[bq].z + wb0.w*xb[bq].w;
                    const float hv1 = wa1.x*xa[bq].x + wa1.y*xa[bq].y + wa1.z*xa[bq].z + wa1.w*xa[bq].w
                                    + wb1.x*xb[bq].x + wb1.y*xb[bq].y + wb1.z*xb[bq].z + wb1.w*xb[bq].w;
                    acc[bq][r0] += hv0;
                    acc[bq][r1] += hv1;
                    (&hq[bq].x)[rp] = pkh(hv0, hv1);
                }
            }
#pragma unroll
            for (int bq = 0; bq < 4; bq++) {
                const int b = bg * 32 + bl0 + bq;
                hatg[(size_t)(b * N_ + n0 + nl) * 64 + le] = hq[bq];
            }
        }
    }

    float* pout = p1 + (size_t)(bg * NSLOT + slot) * (32 * 512);
#pragma unroll
    for (int bq = 0; bq < 4; bq++) {
        float* pb = pout + (bl0 + bq) * 512 + le * 8;
        *(float4*)pb       = make_float4(acc[bq][0]*0.03125f, acc[bq][1]*0.03125f,
                                         acc[bq][2]*0.03125f, acc[bq][3]*0.03125f);
        *(float4*)(pb + 4) = make_float4(acc[bq][4]*0.03125f, acc[bq][5]*0.03125f,
                                         acc[bq][6]*0.03125f, acc[bq][7]*0.03125f);
    }
}

// ---------------- caps_route: one routing pass over materialized fp16 hat --
// R7 route was latency-bound (VALUBusy 8%, occ 30%): grid 512 capped waves at
// 16/CU and loads had zero overlap with the serial softmax chain. Fix: 1024
// blocks (16 n-groups of 72 -> 4 blocks/CU = 32 waves/CU) + software-pipelined
// k-loop (prefetch batch k+1 while computing batch k).
__global__ __launch_bounds__(STH, 2) void caps_route(
    const uint4* __restrict__ hatg, const float* __restrict__ accb,
    float* __restrict__ p2)
{
    __shared__ float red[8 * 512];
    const int b    = blockIdx.x >> 4;
    const int oct  = blockIdx.x & 15;
    const int tid  = threadIdx.x;
    const int w    = tid >> 6;
    const int lane = tid & 63;
    const int c    = lane & 31;
    const int h    = lane >> 5;
    const int le   = 2 * c + h;

    const float* ap = accb + (size_t)b * 512 + le * 8;
    const float4 a0 = *(const float4*)ap;
    const float4 a1 = *(const float4*)(ap + 4);

    float acc[8] = {0.f,0.f,0.f,0.f,0.f,0.f,0.f,0.f};
    const uint4* hb = hatg + (size_t)(b * N_ + oct * 72) * 64 + le;

    uint4 v[2][3];
#pragma unroll
    for (int u = 0; u < 3; u++)
        v[0][u] = hb[(size_t)(w + 8 * u) * 64];

#pragma unroll
    for (int k = 0; k < 3; k++) {
        const int cur = k & 1, nxt = cur ^ 1;
        if (k < 2) {
#pragma unroll
            for (int u = 0; u < 3; u++)
                v[nxt][u] = hb[(size_t)(w + 8 * (3 * (k + 1) + u)) * 64];
        }
#pragma unroll
        for (int u = 0; u < 3; u++) {
            const float2 f0 = uph(v[cur][u].x);
            const float2 f1 = uph(v[cur][u].y);
            const float2 f2 = uph(v[cur][u].z);
            const float2 f3 = uph(v[cur][u].w);
            float lg = f0.x*a0.x + f0.y*a0.y + f1.x*a0.z + f1.y*a0.w
                     + f2.x*a1.x + f2.y*a1.y + f3.x*a1.z + f3.y*a1.w;
            lg += __shfl_xor(lg, 32, 64);        // combine i-halves (same c)
            const float e = __expf(lg);          // no max-subtract: |lg| small
            float s = e;
#pragma unroll
            for (int m = 16; m >= 1; m >>= 1) s += __shfl_xor(s, m, 64);
            const float sc = e * __builtin_amdgcn_rcpf(s);
            acc[0] += sc * f0.x; acc[1] += sc * f0.y;
            acc[2] += sc * f1.x; acc[3] += sc * f1.y;
            acc[4] += sc * f2.x; acc[5] += sc * f2.y;
            acc[6] += sc * f3.x; acc[7] += sc * f3.y;
        }
    }
    // block reduce over 8 waves
    *(float4*)(red + w * 512 + le * 8)     = make_float4(acc[0], acc[1], acc[2], acc[3]);
    *(float4*)(red + w * 512 + le * 8 + 4) = make_float4(acc[4], acc[5], acc[6], acc[7]);
    __syncthreads();
    float vs = 0.f;
#pragma unroll
    for (int s = 0; s < 8; s++) vs += red[s * 512 + tid];
    p2[(size_t)(b * NOCT + oct) * 512 + tid] = vs;
}

// ---------------- caps_r1: reduce caps_hat's 128 slot-slabs (t=0) ----------
__global__ __launch_bounds__(256) void caps_r1(
    const float* __restrict__ p1, float* __restrict__ accb,
    float* __restrict__ out, int t)
{
    const int b   = blockIdx.x >> 2;
    const int q   = blockIdx.x & 3;
    const int tid = threadIdx.x;
    const int e   = q * 128 + (tid >> 1);
    const int p   = tid & 1;
    const int bg  = b >> 5, bl = b & 31;
    const float* base = p1 + (size_t)bg * NSLOT * 16384 + (size_t)bl * 512 + e;
    float v = 0.f;
#pragma unroll 8
    for (int ch = p; ch < NSLOT; ch += 2)
        v += base[(size_t)ch * 16384];
    v += __shfl_xor(v, 1, 64);
    float sq = v * v;
#pragma unroll
    for (int m = 2; m <= 16; m <<= 1) sq += __shfl_xor(sq, m, 64);
    const float scale = sq / (1.f + sq) * rsqrtf(sq + 1e-7f);
    const float ov = v * scale;
    if (p == 0) {
        const int oidx = b * 512 + e;
        if (t == 2) out[oidx] = ov;
        else        accb[oidx] = (t == 0) ? ov : (accb[oidx] + ov);
    }
}

// ---------------- caps_r2: reduce caps_route's 16 oct-slabs per b ----------
__global__ __launch_bounds__(512) void caps_r2(
    const float* __restrict__ p2, float* __restrict__ accb,
    float* __restrict__ out, int t)
{
    const int b = blockIdx.x;
    const int e = threadIdx.x;               // [c=e>>4][i=e&15]
    const float* base = p2 + (size_t)b * (NOCT * 512) + e;
    float v = 0.f;
#pragma unroll
    for (int s = 0; s < NOCT; s++) v += base[s * 512];
    float sq = v * v;
#pragma unroll
    for (int m = 1; m <= 8; m <<= 1) sq += __shfl_xor(sq, m, 64);  // sum over i
    const float scale = sq / (1.f + sq) * rsqrtf(sq + 1e-7f);
    const float ov = v * scale;
    const int oidx = b * 512 + e;
    if (t == 2) out[oidx] = ov;
    else        accb[oidx] += ov;
}

// ---------------- fallback (R5 path, 16.9 MB ws) ---------------------------
__global__ __launch_bounds__(STH, 2) void caps_s_fb(
    const float* __restrict__ X, const float* __restrict__ W,
    const float* __restrict__ aout, float* __restrict__ partials, int t)
{
    __shared__ float wlds[NCH * 64 * 64];
    __shared__ float xlds[NCH * 16 * 8];
    const int bg = blockIdx.x & 3, slot = blockIdx.x >> 2;
    const int tid = threadIdx.x, w = tid >> 6, lane = tid & 63;
    const int c = lane & 31, h = lane >> 5, bl0 = w * 2, sw = c & 7;
    float areg[2][8] = {};
    if (t > 0) {
#pragma unroll
        for (int bq = 0; bq < 2; bq++) {
            const float* ap = aout + (size_t)(bg * 16 + bl0 + bq) * 512 + c * 16 + h * 8;
            const float4 a0 = *(const float4*)ap; const float4 a1 = *(const float4*)(ap + 4);
            areg[bq][0]=a0.x; areg[bq][1]=a0.y; areg[bq][2]=a0.z; areg[bq][3]=a0.w;
            areg[bq][4]=a1.x; areg[bq][5]=a1.y; areg[bq][6]=a1.z; areg[bq][7]=a1.w;
        }
    }
    float acc[2][8];
#pragma unroll
    for (int bq = 0; bq < 2; bq++)
#pragma unroll
        for (int r = 0; r < 8; r++) acc[bq][r] = 0.f;
    for (int cc = 0; cc < 3; cc++) {
        if (cc) __syncthreads();
        const int n0 = (slot + cc * NSLOT) * NCH;
        for (int G = tid; G < NCH * 1024; G += STH) {
            const int nl = G >> 10, f = (G >> 4) & 63, q = G & 15;
            const int wc = f >> 1, wh = f & 1;
            const float4 v = *(const float4*)(W + (size_t)(wc * N_ + n0 + nl) * 128 + wh * 64 + q * 4);
            *(float4*)(wlds + (nl * 64 + f) * 64 + (q ^ (wc & 7)) * 4) = v;
        }
        if (tid < NCH * 32) {
            const int nl = tid >> 5, bl = (tid >> 1) & 15, qx = tid & 1;
            const float4 v = *(const float4*)(X + (size_t)((bg * 16 + bl) * N_ + n0 + nl) * DI_ + qx * 4);
            *(float4*)(xlds + (nl * 16 + bl) * 8 + qx * 4) = v;
        }
        __syncthreads();
#pragma unroll
        for (int nl = 0; nl < NCH; nl++) {
            float4 xa[2], xb[2];
#pragma unroll
            for (int bq = 0; bq < 2; bq++) {
                const float* xp = xlds + (nl * 16 + bl0 + bq) * 8;
                xa[bq] = *(const float4*)xp; xb[bq] = *(const float4*)(xp + 4);
            }
            float hat[2][8];
            const float* frag = wlds + (nl * 64 + 2 * c + h) * 64;
#pragma unroll
            for (int r = 0; r < 8; r++) {
                const int pa = ((2 * r) ^ sw) * 4; const int pb = pa ^ 4;
                const float4 wa = *(const float4*)(frag + pa);
                const float4 wb = *(const float4*)(frag + pb);
#pragma unroll
                for (int bq = 0; bq < 2; bq++)
                    hat[bq][r] = wa.x*xa[bq].x + wa.y*xa[bq].y + wa.z*xa[bq].z + wa.w*xa[bq].w
                               + wb.x*xb[bq].x + wb.y*xb[bq].y + wb.z*xb[bq].z + wb.w*xb[bq].w;
            }
#pragma unroll
            for (int bq = 0; bq < 2; bq++) {
                float softc;
                if (t > 0) {
                    float lg = hat[bq][0]*areg[bq][0] + hat[bq][1]*areg[bq][1]
                             + hat[bq][2]*areg[bq][2] + hat[bq][3]*areg[bq][3]
                             + hat[bq][4]*areg[bq][4] + hat[bq][5]*areg[bq][5]
                             + hat[bq][6]*areg[bq][6] + hat[bq][7]*areg[bq][7];
                    lg += __shfl_xor(lg, 32, 64);
                    const float e = __expf(lg);
                    float s = e;
#pragma unroll
                    for (int m = 16; m >= 1; m >>= 1) s += __shfl_xor(s, m, 64);
                    softc = e / s;
                } else softc = 1.0f / 32.0f;
#pragma unroll
                for (int r = 0; r < 8; r++) acc[bq][r] += softc * hat[bq][r];
            }
        }
    }
    float* pout = partials + (size_t)(bg * NSLOT + slot) * (16 * 512);
#pragma unroll
    for (int bq = 0; bq < 2; bq++) {
        float* pb = pout + (bl0 + bq) * 512 + c * 16 + h * 8;
        *(float4*)pb       = make_float4(acc[bq][0], acc[bq][1], acc[bq][2], acc[bq][3]);
        *(float4*)(pb + 4) = make_float4(acc[bq][4], acc[bq][5], acc[bq][6], acc[bq][7]);
    }
}

__global__ __launch_bounds__(256) void caps_r1_fb(
    const float* __restrict__ partials, float* __restrict__ accb,
    float* __restrict__ out, int t)
{
    const int b   = blockIdx.x >> 2;
    const int q   = blockIdx.x & 3;
    const int tid = threadIdx.x;
    const int e   = q * 128 + (tid >> 1);
    const int p   = tid & 1;
    const int bg  = b >> 4, bl = b & 15;
    const float* base = partials + (size_t)bg * NSLOT * 8192 + (size_t)bl * 512 + e;
    float v = 0.f;
#pragma unroll 8
    for (int ch = p; ch < NSLOT; ch += 2)
        v += base[(size_t)ch * 8192];
    v += __shfl_xor(v, 1, 64);
    float sq = v * v;
#pragma unroll
    for (int m = 2; m <= 16; m <<= 1) sq += __shfl_xor(sq, m, 64);
    const float scale = sq / (1.f + sq) * rsqrtf(sq + 1e-7f);
    const float ov = v * scale;
    if (p == 0) {
        const int oidx = b * 512 + e;
        if (t == 2) out[oidx] = ov;
        else        accb[oidx] = (t == 0) ? ov : (accb[oidx] + ov);
    }
}

extern "C" void kernel_launch(void* const* d_in, const int* in_sizes, int n_in,
                              void* d_out, int out_size, void* d_ws, size_t ws_size,
                              hipStream_t stream) {
    const float* X = (const float*)d_in[0];   // [B,N,DI]
    const float* W = (const float*)d_in[1];   // [C,N,DC,DI]
    float* out = (float*)d_out;               // [B,C,DC]

    const size_t hat_b = (size_t)B_ * N_ * 512 * 2;      // 75,497,472 (fp16)
    const size_t p1_b  = (size_t)256 * 16384 * 4;        // 16,777,216
    const size_t p2_b  = (size_t)B_ * NOCT * 512 * 4;    //  2,097,152
    const size_t acc_b = (size_t)B_ * 512 * 4;           //    131,072

    if (ws_size >= hat_b + p1_b + p2_b + acc_b) {
        char* ws = (char*)d_ws;
        uint4* hatg = (uint4*)ws;
        float* p1   = (float*)(ws + hat_b);
        float* p2   = (float*)(ws + hat_b + p1_b);
        float* accb = (float*)(ws + hat_b + p1_b + p2_b);
        caps_hat  <<<256, STH, 0, stream>>>(X, W, hatg, p1);
        caps_r1   <<<256, 256, 0, stream>>>(p1, accb, out, 0);
        caps_route<<<B_ * NOCT, STH, 0, stream>>>(hatg, accb, p2);
        caps_r2   <<<64, 512, 0, stream>>>(p2, accb, out, 1);
        caps_route<<<B_ * NOCT, STH, 0, stream>>>(hatg, accb, p2);
        caps_r2   <<<64, 512, 0, stream>>>(p2, accb, out, 2);
    } else {
        float* partials = (float*)d_ws;
        float* accb = partials + (size_t)512 * 8192;
        for (int t = 0; t < 3; t++) {
            caps_s_fb<<<512, STH, 0, stream>>>(X, W, accb, partials, t);
            caps_r1_fb<<<256, 256, 0, stream>>>(partials, accb, out, t);
        }
    }
}